// Round 7
// baseline (1920.193 us; speedup 1.0000x reference)
//
#include <hip/hip_runtime.h>
#include <stdint.h>

typedef unsigned long long u64;

#define NB   32
#define TST  384
#define IDM  64
#define HDM  128
#define NCLS 10
#define EPSF 1e-7f
#define LOG2E 1.44269504088896340736f

// LDS layout (float offsets)
#define O_SBUF 0      // 385 (pad->388)  cached s_buf[t']
#define O_WLDS 388    // 388             attention weights w[t']
#define O_ACT  776    // 192             [x_t(64) | h(128)] activations
#define O_GEX  968    // 512             FC feature [h|attn] in [0..256); IDX ints in [0..384)
#define O_RED  1480   // 1024            gate exchange (S1, [0..512)) + attn partials (S6, 8x128)
#define O_DELT 2504   // 32              deltas from all batches
#define O_WFC  2536   // 10*264 = 2640   padded W_fc
#define O_BFC  5176   // 12
#define O_MISC 5188   // 32: [0]=s_h, [2..10)=wsp, ints[16..24)=counts
#define SMTOT  5220

__device__ __forceinline__ float sigm(float x) {
  return 1.0f / (1.0f + __builtin_amdgcn_exp2f(-LOG2E * x));
}
__device__ __forceinline__ float tanh_f(float x) {
  return 1.0f - 2.0f / (1.0f + __builtin_amdgcn_exp2f(2.0f * LOG2E * x));
}

// full-rate DPP add (VALU pipe, vs ds_bpermute for __shfl_xor)
template <int CTRL>
__device__ __forceinline__ float dppadd(float v) {
  int t = __builtin_amdgcn_update_dpp(0, __builtin_bit_cast(int, v), CTRL, 0xF, 0xF, true);
  return v + __builtin_bit_cast(float, t);
}
// sum within aligned 8-lane octet (xor1, xor2, then cross-quad via half-mirror)
__device__ __forceinline__ float sum8(float v) {
  v = dppadd<0xB1>(v);   // quad_perm xor1
  v = dppadd<0x4E>(v);   // quad_perm xor2
  v = dppadd<0x141>(v);  // row_half_mirror: other quad within octet (quad-uniform by now)
  return v;
}
// sum within aligned 16-lane group
__device__ __forceinline__ float sum16(float v) {
  v = dppadd<0xB1>(v);
  v = dppadd<0x4E>(v);
  v = dppadd<0x141>(v);
  v = dppadd<0x140>(v);  // row_mirror: other octet within row of 16
  return v;
}
// full wave64 sum
__device__ __forceinline__ float wave_sum(float v) {
  v = sum16(v);
  v += __shfl_xor(v, 16, 64);
  v += __shfl_xor(v, 32, 64);
  return v;
}

// System-scope (sc0 sc1) 8B mailbox ops: bypass L1/L2, meet at the memory-side
// Infinity Cache. No cache-invalidate side effects (agent-scope acquire was
// nuking the XCD L2 every poll iteration).
__device__ __forceinline__ void mail_store(u64* p, u64 v) {
  asm volatile("global_store_dwordx2 %0, %1, off sc0 sc1"
               :: "v"(p), "v"(v) : "memory");
}
__device__ __forceinline__ u64 mail_load(u64* p) {
  u64 v;
  asm volatile("global_load_dwordx2 %0, %1, off sc0 sc1\n\t"
               "s_waitcnt vmcnt(0)"
               : "=v"(v) : "v"(p) : "memory");
  return v;
}

__global__ __launch_bounds__(512, 2)
void sab_kernel(const float* __restrict__ x, const float* __restrict__ Wih,
                const float* __restrict__ Whh, const float* __restrict__ bihp,
                const float* __restrict__ bhhp, const float* __restrict__ wtp,
                const float* __restrict__ Wfcp, const float* __restrict__ bfcp,
                float* __restrict__ dout, u64* __restrict__ mail) {
  __shared__ __align__(16) float SM[SMTOT];
  int* IMISC = (int*)(SM + O_MISC);   // ints at slots 16..23 (counts)
  int* IDX   = (int*)(SM + O_GEX);    // compacted t' indices (reuses GEX)

  const int tid  = threadIdx.x;
  const int lane = tid & 63;
  const int wvid = tid >> 6;
  const int b    = blockIdx.x;
  const int go   = tid >> 3;          // gate octet 0..63
  const int kc   = tid & 7;           // K-chunk 0..7 (24 cols each)

  float* hsout = dout + (size_t)NB * TST * NCLS;     // hs region == attention buf
  const float* myx = x + (size_t)b * TST * IDM;

  // ---- preload weight sub-block: rows 8*go..8*go+7, cols 24*kc..24*kc+23 ----
  float w[8][24];
  #pragma unroll
  for (int i = 0; i < 8; ++i) {
    const int g = 8 * go + i;
    #pragma unroll
    for (int j = 0; j < 24; ++j) {
      const int k = 24 * kc + j;
      const float* sp = (k < IDM) ? (Wih + g * IDM + k) : (Whh + g * HDM + (k - IDM));
      w[i][j] = *sp;
    }
  }
  const float bias = bihp[tid] + bhhp[tid];

  // wave-0-only: scoring weights for its two hidden dims (j0=lane, j1=lane+64)
  float wt00 = 0.f, wt01 = 0.f, wt10 = 0.f, wt11 = 0.f;
  if (wvid == 0) {
    wt00 = wtp[lane];        wt01 = wtp[64 + lane];
    wt10 = wtp[128 + lane];  wt11 = wtp[192 + lane];
  }
  float cst0 = 0.f, cst1 = 0.f, hc0 = 0.f, hc1 = 0.f;

  // incremental top-5 of s_buf (tid 0 only); s_buf[0]=0 pre-inserted
  float t5a = 0.f, t5b = -3e38f, t5c = -3e38f, t5d = -3e38f, t5e = -3e38f;

  // ---- init LDS ----
  for (int idx = tid; idx < NCLS * 256; idx += 512) {
    const int c = idx >> 8, k = idx & 255;
    SM[O_WFC + c * 264 + k] = Wfcp[idx];
  }
  if (tid < NCLS) SM[O_BFC + tid] = bfcp[tid];
  if (tid < HDM) SM[O_ACT + 64 + tid] = 0.f;   // h0 = 0
  if (tid < IDM) SM[O_ACT + tid] = myx[tid];   // x_0
  if (tid == 0) {
    SM[O_SBUF] = 0.f;
    mail_store(&mail[b], 0ull);
    mail_store(&mail[NB + b], 0ull);
  }
  __syncthreads();

  for (int t = 0; t < TST; ++t) {
    const int r = t + 1;
    const bool big = (r > 5);

    // ================= gates: g = [x|h] @ W^T + bias =================
    float acc[8] = {0,0,0,0,0,0,0,0};
    {
      const float4* a4 = reinterpret_cast<const float4*>(SM + O_ACT + kc * 24);
      #pragma unroll
      for (int m = 0; m < 6; ++m) {
        const float4 av = a4[m];
        #pragma unroll
        for (int i = 0; i < 8; ++i) {
          acc[i] = fmaf(av.x, w[i][4*m+0], acc[i]);
          acc[i] = fmaf(av.y, w[i][4*m+1], acc[i]);
          acc[i] = fmaf(av.z, w[i][4*m+2], acc[i]);
          acc[i] = fmaf(av.w, w[i][4*m+3], acc[i]);
        }
      }
    }
    #pragma unroll
    for (int i = 0; i < 8; ++i) acc[i] = sum8(acc[i]);   // octet butterfly, VALU-only
    float pre = acc[0];
    #pragma unroll
    for (int i = 1; i < 8; ++i) if (kc == i) pre = acc[i];  // this thread's gate = tid
    pre += bias;
    const bool tg = (tid >= 256) && (tid < 384);            // gg gates -> tanh
    SM[O_RED + tid] = tg ? tanh_f(pre) : sigm(pre);         // gate exchange in RED
    __syncthreads();                                        // S1

    // ============ exchange window: cell+publish | poll | FC | x-prefetch ========
    if (wvid == 0) {
      // LSTM cell for j0=lane, j1=lane+64 — publish path, shortest possible
      const float i0 = SM[O_RED + lane],        i1 = SM[O_RED + 64 + lane];
      const float f0 = SM[O_RED + 128 + lane],  f1 = SM[O_RED + 192 + lane];
      const float g0 = SM[O_RED + 256 + lane],  g1 = SM[O_RED + 320 + lane];
      const float o0 = SM[O_RED + 384 + lane],  o1 = SM[O_RED + 448 + lane];
      cst0 = f0 * cst0 + i0 * g0;
      cst1 = f1 * cst1 + i1 * g1;
      hc0  = o0 * tanh_f(cst0);
      hc1  = o1 * tanh_f(cst1);
      float th = tanh_f(hc0) * wt00 + tanh_f(hc1) * wt01;
      th = wave_sum(th);                         // s_h, uniform across wave 0
      if (lane == 0) {
        SM[O_MISC] = th;
        if (big) {
          const u64 pv = (((u64)(unsigned)r) << 32) | (u64)__float_as_uint(t5e + th + EPSF);
          mail_store(&mail[(r & 1) * NB + b], pv);
        }
      }
    } else if (wvid == 7) {
      if (big && lane < NB) {                    // sleep-free poll, sc0sc1 loads
        u64* slot = &mail[(r & 1) * NB + lane];
        u64 v = mail_load(slot);
        while ((unsigned)(v >> 32) != (unsigned)r) v = mail_load(slot);
        SM[O_DELT + lane] = __uint_as_float((unsigned)v);
      }
    } else if (wvid == 1) {
      if (t + 1 < TST && lane < IDM)             // x_{t+1} -> ACT (gates read after S7)
        SM[O_ACT + lane] = myx[(size_t)(t + 1) * IDM + lane];
    } else if (t > 0 && tid < 288) {             // waves 2-4: FC for step t-1
      const int cls = (tid - 128) >> 4, p = tid & 15;
      float pt = 0.f;
      #pragma unroll
      for (int i = 0; i < 16; ++i) {
        const int k = p + 16 * i;
        pt = fmaf(SM[O_WFC + cls * 264 + k], SM[O_GEX + k], pt);
      }
      pt = sum16(pt);
      if (p == 0) dout[((size_t)(b * TST + (t - 1))) * NCLS + cls] = pt + SM[O_BFC + cls];
    }
    __syncthreads();                                        // S3

    const float s_h = SM[O_MISC];

    // ================= attention weights =================
    float wval = 0.f;
    bool pred = false;
    if (big) {
      if (tid < r) {
        const float sc = s_h + SM[O_SBUF + tid];
        wval = fmaxf(sc - SM[O_DELT + ((b * r + tid) & (NB - 1))], 0.f);
        SM[O_WLDS + tid] = wval;
        pred = (wval > 0.f) && (tid > 0);   // t'=0 row is zeros: no contribution
      }
    } else {
      float scv = (tid < r) ? (s_h + SM[O_SBUF + tid]) : -3e38f;
      float mx = scv;
      #pragma unroll
      for (int s = 1; s < 64; s <<= 1) mx = fmaxf(mx, __shfl_xor(mx, s, 64));
      if (tid < r) {
        wval = __builtin_amdgcn_exp2f(LOG2E * (scv - mx));
        SM[O_WLDS + tid] = wval;
        pred = (tid > 0);
      }
    }
    const float wsp = wave_sum(wval);
    if (lane == 0) SM[O_MISC + 2 + wvid] = wsp;
    const u64 bmask = __ballot((int)pred);
    if (lane == 0) IMISC[16 + wvid] = (int)__popcll(bmask);
    __syncthreads();                                        // S4

    int wbase = 0, nnz = 0;
    #pragma unroll
    for (int i = 0; i < 8; ++i) {
      const int c = IMISC[16 + i];
      if (i < wvid) wbase += c;
      nnz += c;
    }
    if (pred) {
      const int pos = wbase + (int)__popcll(bmask & ((1ull << lane) - 1ull));
      IDX[pos] = tid;
    }
    __syncthreads();                                        // S5

    // ============ attn_c: sparse gather over buf (== hs rows), UNNORMALIZED ======
    const int j8 = tid & 15, q = tid >> 4;
    float ac[8] = {0,0,0,0,0,0,0,0};
    for (int ii = q; ii < nnz; ii += 32) {
      const int tp = IDX[ii];                                // t' index (>=1)
      const float wgt = SM[O_WLDS + tp];
      const float* bp = hsout + ((size_t)(b * TST + tp - 1)) * HDM + j8 * 8;
      const float4 v0 = *reinterpret_cast<const float4*>(bp);
      const float4 v1 = *reinterpret_cast<const float4*>(bp + 4);
      ac[0] = fmaf(wgt, v0.x, ac[0]); ac[1] = fmaf(wgt, v0.y, ac[1]);
      ac[2] = fmaf(wgt, v0.z, ac[2]); ac[3] = fmaf(wgt, v0.w, ac[3]);
      ac[4] = fmaf(wgt, v1.x, ac[4]); ac[5] = fmaf(wgt, v1.y, ac[5]);
      ac[6] = fmaf(wgt, v1.z, ac[6]); ac[7] = fmaf(wgt, v1.w, ac[7]);
    }
    #pragma unroll
    for (int i = 0; i < 8; ++i) {     // reduce the 4 q-groups inside each wave
      ac[i] += __shfl_xor(ac[i], 16, 64);
      ac[i] += __shfl_xor(ac[i], 32, 64);
    }
    if ((q & 3) == 0) {
      float4* r4 = reinterpret_cast<float4*>(SM + O_RED + wvid * 128 + j8 * 8);
      r4[0] = make_float4(ac[0], ac[1], ac[2], ac[3]);
      r4[1] = make_float4(ac[4], ac[5], ac[6], ac[7]);
    }
    __syncthreads();                                        // S6

    // ================= finalize (wave 0): h, outputs, s_buf[r], top-5 ==========
    if (wvid == 0) {
      float wsum = 0.f;
      #pragma unroll
      for (int i = 0; i < 8; ++i) wsum += SM[O_MISC + 2 + i];
      const float inv = 1.0f / (wsum + (big ? EPSF : 0.f));
      float at0 = 0.f, at1 = 0.f;
      #pragma unroll
      for (int wv2 = 0; wv2 < 8; ++wv2) {
        at0 += SM[O_RED + wv2 * 128 + lane];
        at1 += SM[O_RED + wv2 * 128 + 64 + lane];
      }
      at0 *= inv; at1 *= inv;
      const float hf0 = hc0 + at0, hf1 = hc1 + at1;
      const size_t row = ((size_t)(b * TST + t)) * HDM;
      hsout[row + lane]      = hf0;
      hsout[row + 64 + lane] = hf1;
      SM[O_ACT + 64 + lane]  = hf0;    // h for next step's gates
      SM[O_ACT + 128 + lane] = hf1;
      SM[O_GEX + lane]       = hf0;    // FC input [h | attn_c]
      SM[O_GEX + 64 + lane]  = hf1;
      SM[O_GEX + 128 + lane] = at0;
      SM[O_GEX + 192 + lane] = at1;
      float tb = tanh_f(hf0) * wt10 + tanh_f(hf1) * wt11;
      tb = wave_sum(tb);
      if (lane == 0 && r < TST) {
        SM[O_SBUF + r] = tb;
        if (tb > t5e) {                // maintain 5 largest s_buf values
          if (tb > t5a)      { t5e=t5d; t5d=t5c; t5c=t5b; t5b=t5a; t5a=tb; }
          else if (tb > t5b) { t5e=t5d; t5d=t5c; t5c=t5b; t5b=tb; }
          else if (tb > t5c) { t5e=t5d; t5d=t5c; t5c=tb; }
          else if (tb > t5d) { t5e=t5d; t5d=tb; }
          else               { t5e=tb; }
        }
      }
    }
    __syncthreads();                                        // S7 (loop end)
  }

  // final FC for t = 383 (reads GEX written at last finalize)
  if (tid < 160) {
    const int cls = tid >> 4, p = tid & 15;
    float pt = 0.f;
    #pragma unroll
    for (int i = 0; i < 16; ++i) {
      const int k = p + 16 * i;
      pt = fmaf(SM[O_WFC + cls * 264 + k], SM[O_GEX + k], pt);
    }
    pt = sum16(pt);
    if (p == 0) dout[((size_t)(b * TST + (TST - 1))) * NCLS + cls] = pt + SM[O_BFC + cls];
  }
}

extern "C" void kernel_launch(void* const* d_in, const int* in_sizes, int n_in,
                              void* d_out, int out_size, void* d_ws, size_t ws_size,
                              hipStream_t stream) {
  const float* x   = (const float*)d_in[0];
  const float* Wih = (const float*)d_in[1];
  const float* Whh = (const float*)d_in[2];
  const float* bih = (const float*)d_in[3];
  const float* bhh = (const float*)d_in[4];
  const float* wt  = (const float*)d_in[5];
  const float* Wfc = (const float*)d_in[6];
  const float* bfc = (const float*)d_in[7];
  sab_kernel<<<dim3(NB), dim3(512), 0, stream>>>(
      x, Wih, Whh, bih, bhh, wt, Wfc, bfc, (float*)d_out, (u64*)d_ws);
}